// Round 12
// baseline (1107.997 us; speedup 1.0000x reference)
//
#include <hip/hip_runtime.h>

typedef __bf16 bf16;
typedef __bf16 bf16x8 __attribute__((ext_vector_type(8)));
typedef float f32x4 __attribute__((ext_vector_type(4)));

#define Tt 64
#define Bb 1024
#define Dd 128
#define Ee 256
#define Hh 512
#define H3 1536

__device__ __forceinline__ float sigmf(float x) { return 1.0f / (1.0f + __expf(-x)); }
__device__ __forceinline__ float tanhfast(float x) {
    float e = __expf(2.0f * x);
    return 1.0f - 2.0f / (e + 1.0f);
}

// agent-scope (device-coherent) ops; sc1 = bypass L2 to the memory-side L3.
#define LD_SC(dst, bp, OFF) \
    asm volatile("global_load_dwordx4 %0, %1, off offset:" #OFF " sc1" : "=&v"(dst) : "v"(bp))
#define ST_SC(bp, OFF, val) \
    asm volatile("global_store_short %0, %1, off offset:" #OFF " sc1" :: "v"(bp), "v"(val))

// ---------------- fused weight prep: f32 [K][N] -> bf16 [N][K] for all 6 weights ----------------
__global__ void k_prep(const float* __restrict__ We, const float* __restrict__ Wie, const float* __restrict__ Whe,
                       const float* __restrict__ Wid, const float* __restrict__ Whd, const float* __restrict__ Wo,
                       bf16* __restrict__ dWe, bf16* __restrict__ dWie, bf16* __restrict__ dWhe,
                       bf16* __restrict__ dWid, bf16* __restrict__ dWhd, bf16* __restrict__ dWo) {
    long i = (long)blockIdx.x * 256 + threadIdx.x;
    const float* s;
    bf16* d;
    int K, N;
    if (i < 32768) { s = We; d = dWe; K = Dd; N = Ee; }
    else if ((i -= 32768) < 393216) { s = Wie; d = dWie; K = Ee; N = H3; }
    else if ((i -= 393216) < 786432) { s = Whe; d = dWhe; K = Hh; N = H3; }
    else if ((i -= 786432) < 393216) { s = Wid; d = dWid; K = Ee; N = H3; }
    else if ((i -= 393216) < 786432) { s = Whd; d = dWhd; K = Hh; N = H3; }
    else if ((i -= 786432) < 65536) { s = Wo; d = dWo; K = Hh; N = Dd; }
    else return;
    int n = (int)(i / K), k = (int)(i - (long)n * K);
    d[i] = (bf16)s[(size_t)k * N + n];
}

// ---------------- embed: relu(x @ W_emb + b); past (z=0) and future (z=1) fused ----------------
__global__ __launch_bounds__(256) void k_embed(const float* __restrict__ xP, const float* __restrict__ xF,
                                               const bf16* __restrict__ WT, const float* __restrict__ bias,
                                               bf16* __restrict__ oP, bf16* __restrict__ oF) {
    const int lane = threadIdx.x & 63, wv = threadIdx.x >> 6;
    const float* x = blockIdx.z ? xF : xP;
    bf16* o = blockIdx.z ? oF : oP;
    const int m0w = blockIdx.x * 128 + wv * 32;
    const int c0 = blockIdx.y * 64;
    const int koff = (lane >> 4) * 8;
    f32x4 acc[2][4];
#pragma unroll
    for (int m = 0; m < 2; ++m)
#pragma unroll
        for (int s = 0; s < 4; ++s) acc[m][s] = f32x4{0.f, 0.f, 0.f, 0.f};

    const float* xp0 = x + (size_t)(m0w + (lane & 15)) * Dd + koff;
#pragma unroll
    for (int kc = 0; kc < 4; ++kc) {
        bf16x8 a0, a1;
        {
            float4 f0 = *(const float4*)(xp0 + kc * 32);
            float4 f1 = *(const float4*)(xp0 + kc * 32 + 4);
            a0[0] = (bf16)f0.x; a0[1] = (bf16)f0.y; a0[2] = (bf16)f0.z; a0[3] = (bf16)f0.w;
            a0[4] = (bf16)f1.x; a0[5] = (bf16)f1.y; a0[6] = (bf16)f1.z; a0[7] = (bf16)f1.w;
            float4 g0 = *(const float4*)(xp0 + 16 * Dd + kc * 32);
            float4 g1 = *(const float4*)(xp0 + 16 * Dd + kc * 32 + 4);
            a1[0] = (bf16)g0.x; a1[1] = (bf16)g0.y; a1[2] = (bf16)g0.z; a1[3] = (bf16)g0.w;
            a1[4] = (bf16)g1.x; a1[5] = (bf16)g1.y; a1[6] = (bf16)g1.z; a1[7] = (bf16)g1.w;
        }
#pragma unroll
        for (int s = 0; s < 4; ++s) {
            bf16x8 b = *(const bf16x8*)(WT + (size_t)(c0 + s * 16 + (lane & 15)) * Dd + kc * 32 + koff);
            acc[0][s] = __builtin_amdgcn_mfma_f32_16x16x32_bf16(a0, b, acc[0][s], 0, 0, 0);
            acc[1][s] = __builtin_amdgcn_mfma_f32_16x16x32_bf16(a1, b, acc[1][s], 0, 0, 0);
        }
    }
#pragma unroll
    for (int m = 0; m < 2; ++m)
#pragma unroll
        for (int s = 0; s < 4; ++s) {
            int col = c0 + s * 16 + (lane & 15);
            float bv = bias[col];
#pragma unroll
            for (int r = 0; r < 4; ++r) {
                int row = m0w + m * 16 + (lane >> 4) * 4 + r;
                o[(size_t)row * Ee + col] = (bf16)fmaxf(acc[m][s][r] + bv, 0.0f);
            }
        }
}

// ---------------- persistent cooperative GRU v6: 32x16 wave tile (2 MFMAs per B read) ----------------
// 256 blocks = 16 groups (im) x 16 col-blocks (in); XCD-affine remap. 4 waves/block:
// rh = wv>>1 (32-row half), ch = wv&1 (16-col half). Each B fragment from LDS feeds TWO
// row-fragment MFMAs -> LDS B-read traffic 288 reads/CU/step (round 11: 576).
// Sync domain = (im, rh): 32 waves (16 blocks x 2 ch), per-wave sc1 flags, per-peer
// pipelined HSTEP waits (flags 2p,2p+1 per peer block). No per-step __syncthreads.
// Compute lambdas = round 3 (proven); sync = round 6/11 (proven).
__global__ __launch_bounds__(256, 1) void k_gru_all(
    const bf16* __restrict__ embP, const bf16* __restrict__ embF, const float* __restrict__ noise,
    const bf16* __restrict__ WihE, const bf16* __restrict__ WhhE,
    const float* __restrict__ bIhE, const float* __restrict__ bHhE,
    const bf16* __restrict__ WihD, const bf16* __restrict__ WhhD,
    const float* __restrict__ bIhD, const float* __restrict__ bHhD,
    bf16* __restrict__ hA, bf16* __restrict__ hB, bf16* __restrict__ ys, unsigned* __restrict__ flags) {
    __shared__ bf16 Wih[6 * 8 * 64 * 8];    // 49152 B: [s=gate*2+f][kc8][lane]x8
    __shared__ bf16 Whh[6 * 16 * 64 * 8];   // 98304 B: [s=gate*2+f][kc16][lane]x8
    const int tid = threadIdx.x;
    const int lane = tid & 63, wv = tid >> 6;
    const int bid = blockIdx.x;
    const int im = (bid & 7) * 2 + (bid >> 7);   // group 0..15; xcd = bid&7
    const int in = (bid >> 3) & 15;              // col block 0..15
    const int rh = wv >> 1, ch = wv & 1;
    const int rowb = im * 64 + rh * 32;          // wave's 32 rows
    const int arow0 = rowb + (lane & 15);        // A row, fragment 0 (fragment 1: +16)
    const int koff = (lane >> 4) * 8;
    const int colc = in * 32 + ch * 16 + (lane & 15);
    unsigned* dom = flags + ((size_t)im * 2 + rh) * 32 * 16;  // 32 flags x 64B
    const int myidx = in * 2 + ch;

    const bf16x8* WihV = (const bf16x8*)Wih;
    const bf16x8* WhhV = (const bf16x8*)Whh;

    auto stage = [&](const bf16* WT, int Kdim, int KC, bf16* lds) {
        int total = 6 * KC * 64;
        for (int idx = tid; idx < total; idx += 256) {
            int ln = idx & 63;
            int kc = (idx >> 6) % KC;
            int s = (idx >> 6) / KC;
            int gate = s >> 1, f = s & 1;
            int col = gate * Hh + in * 32 + f * 16 + (ln & 15);
            int k = kc * 32 + (ln >> 4) * 8;
            *(bf16x8*)(lds + (size_t)idx * 8) = *(const bf16x8*)(WT + (size_t)col * Kdim + k);
        }
    };

    float bi[3], bh[3];
    auto load_bias = [&](const float* bIh, const float* bHh) {
#pragma unroll
        for (int g = 0; g < 3; ++g) {
            bi[g] = bIh[g * Hh + colc];
            bh[g] = bHh[g * Hh + colc];
        }
    };

    // per-WAVE release: my sc1 stores acked at L3 -> lane0 publishes seq. No block barrier.
    auto signal = [&](unsigned seq) {
        asm volatile("s_waitcnt vmcnt(0)" ::: "memory");
        if (lane == 0) {
            unsigned* fp = dom + myidx * 16;
            asm volatile("global_store_dword %0, %1, off sc1" :: "v"(fp), "v"(seq) : "memory");
        }
    };
    // one poll: lane k loads flag (k&31) -> 64-bit ballot
    auto poll = [&](unsigned seq) -> unsigned long long {
        unsigned v;
        const unsigned* fp = dom + (lane & 31) * 16;
        asm volatile("global_load_dword %0, %1, off sc1\n\ts_waitcnt vmcnt(0)"
                     : "=&v"(v) : "v"(fp) : "memory");
        return __ballot((int)(v >= seq));
    };
    auto wait_all = [&](unsigned seq) {
        while (poll(seq) != ~0ULL) __builtin_amdgcn_s_sleep(2);
    };

    f32x4 aR[2], aZ[2], aNX[2], aNH[2];
    auto zacc = [&]() {
#pragma unroll
        for (int i = 0; i < 2; ++i) {
            aR[i] = f32x4{0.f, 0.f, 0.f, 0.f};
            aZ[i] = f32x4{0.f, 0.f, 0.f, 0.f};
            aNX[i] = f32x4{0.f, 0.f, 0.f, 0.f};
            aNH[i] = f32x4{0.f, 0.f, 0.f, 0.f};
        }
    };

    auto xp_phase = [&](const bf16* xp) {
        const bf16* a0p = xp + (size_t)arow0 * Ee + koff;
#pragma unroll
        for (int kc = 0; kc < 8; ++kc) {
            bf16x8 a0 = *(const bf16x8*)(a0p + kc * 32);
            bf16x8 a1 = *(const bf16x8*)(a0p + 16 * Ee + kc * 32);
            bf16x8 br = WihV[((0 + ch) * 8 + kc) * 64 + lane];
            bf16x8 bz = WihV[((2 + ch) * 8 + kc) * 64 + lane];
            bf16x8 bn = WihV[((4 + ch) * 8 + kc) * 64 + lane];
            aR[0] = __builtin_amdgcn_mfma_f32_16x16x32_bf16(a0, br, aR[0], 0, 0, 0);
            aR[1] = __builtin_amdgcn_mfma_f32_16x16x32_bf16(a1, br, aR[1], 0, 0, 0);
            aZ[0] = __builtin_amdgcn_mfma_f32_16x16x32_bf16(a0, bz, aZ[0], 0, 0, 0);
            aZ[1] = __builtin_amdgcn_mfma_f32_16x16x32_bf16(a1, bz, aZ[1], 0, 0, 0);
            aNX[0] = __builtin_amdgcn_mfma_f32_16x16x32_bf16(a0, bn, aNX[0], 0, 0, 0);
            aNX[1] = __builtin_amdgcn_mfma_f32_16x16x32_bf16(a1, bn, aNX[1], 0, 0, 0);
        }
    };

    // hW with per-peer pipelined waits: K-chunk kc=p holds peer block p's columns
    // (written by waves with flags 2p, 2p+1).
    auto hw_phase = [&](const bf16* hp, unsigned seq) {
        const bf16* h0p = hp + (size_t)arow0 * Hh + koff;
        const bf16* h1p = h0p + 16 * Hh;
        bf16x8 h0[16], h1[16];
        unsigned long long rdy = poll(seq);
#define HSTEP(p, OFF) \
        while (((rdy >> (2 * p)) & 3ULL) != 3ULL) { __builtin_amdgcn_s_sleep(2); rdy = poll(seq); } \
        LD_SC(h0[p], h0p, OFF); \
        LD_SC(h1[p], h1p, OFF);
        HSTEP(0, 0)    HSTEP(1, 64)   HSTEP(2, 128)  HSTEP(3, 192)
        HSTEP(4, 256)  HSTEP(5, 320)  HSTEP(6, 384)  HSTEP(7, 448)
        HSTEP(8, 512)  HSTEP(9, 576)  HSTEP(10, 640) HSTEP(11, 704)
        HSTEP(12, 768) HSTEP(13, 832) HSTEP(14, 896) HSTEP(15, 960)
#undef HSTEP
        asm volatile("s_waitcnt vmcnt(0)" ::: "memory");
        __builtin_amdgcn_sched_barrier(0);
#pragma unroll
        for (int kc = 0; kc < 16; ++kc) {
            bf16x8 br = WhhV[((0 + ch) * 16 + kc) * 64 + lane];
            bf16x8 bz = WhhV[((2 + ch) * 16 + kc) * 64 + lane];
            bf16x8 bn = WhhV[((4 + ch) * 16 + kc) * 64 + lane];
            aR[0] = __builtin_amdgcn_mfma_f32_16x16x32_bf16(h0[kc], br, aR[0], 0, 0, 0);
            aR[1] = __builtin_amdgcn_mfma_f32_16x16x32_bf16(h1[kc], br, aR[1], 0, 0, 0);
            aZ[0] = __builtin_amdgcn_mfma_f32_16x16x32_bf16(h0[kc], bz, aZ[0], 0, 0, 0);
            aZ[1] = __builtin_amdgcn_mfma_f32_16x16x32_bf16(h1[kc], bz, aZ[1], 0, 0, 0);
            aNH[0] = __builtin_amdgcn_mfma_f32_16x16x32_bf16(h0[kc], bn, aNH[0], 0, 0, 0);
            aNH[1] = __builtin_amdgcn_mfma_f32_16x16x32_bf16(h1[kc], bn, aNH[1], 0, 0, 0);
        }
    };

    float hreg[8];
#pragma unroll
    for (int i = 0; i < 8; ++i) hreg[i] = 0.0f;

    auto epi = [&](bf16* op) {
#pragma unroll
        for (int rf = 0; rf < 2; ++rf) {
            bf16* stb = op + (size_t)(rowb + rf * 16 + (lane >> 4) * 4) * Hh + colc;
            unsigned short us[4];
#pragma unroll
            for (int r = 0; r < 4; ++r) {
                float rg = sigmf(aR[rf][r] + bi[0] + bh[0]);
                float zg = sigmf(aZ[rf][r] + bi[1] + bh[1]);
                float ng = tanhfast(aNX[rf][r] + bi[2] + rg * (aNH[rf][r] + bh[2]));
                float hv = (1.0f - zg) * ng + zg * hreg[rf * 4 + r];
                hreg[rf * 4 + r] = hv;
                us[r] = __builtin_bit_cast(unsigned short, (bf16)hv);
            }
            ST_SC(stb, 0, us[0]);
            ST_SC(stb, 1024, us[1]);
            ST_SC(stb, 2048, us[2]);
            ST_SC(stb, 3072, us[3]);
        }
    };

    // ---------- encoder ----------
    stage(WihE, Ee, 8, Wih);
    stage(WhhE, Hh, 16, Whh);
    load_bias(bIhE, bHhE);
    __syncthreads();

#pragma unroll 1
    for (int t = 0; t < Tt; ++t) {
        zacc();
        xp_phase(embP + (size_t)t * Bb * Ee);
        if (t > 0) hw_phase(((t - 1) & 1) ? hB : hA, (unsigned)t);
        epi((t & 1) ? hB : hA);
        signal((unsigned)(t + 1));  // seq 1..64
    }

    // ---------- hidden = h_enc + noise; switch to decoder weights ----------
    wait_all((unsigned)Tt);  // (im,rh) peers done with enc step 63 (incl. hA reads)
    {
#pragma unroll
        for (int rf = 0; rf < 2; ++rf) {
            bf16* stb = hA + (size_t)(rowb + rf * 16 + (lane >> 4) * 4) * Hh + colc;
            unsigned short us[4];
#pragma unroll
            for (int r = 0; r < 4; ++r) {
                int row = rowb + rf * 16 + (lane >> 4) * 4 + r;
                float v = hreg[rf * 4 + r] + noise[(size_t)row * Hh + colc];
                hreg[rf * 4 + r] = v;
                us[r] = __builtin_bit_cast(unsigned short, (bf16)v);
            }
            ST_SC(stb, 0, us[0]);
            ST_SC(stb, 1024, us[1]);
            ST_SC(stb, 2048, us[2]);
            ST_SC(stb, 3072, us[3]);
        }
    }
    __syncthreads();  // all waves of this block past their enc LDS reads
    stage(WihD, Ee, 8, Wih);
    stage(WhhD, Hh, 16, Whh);
    __syncthreads();  // decoder LDS staged before any wave's dec reads
    load_bias(bIhD, bHhD);
    signal((unsigned)(Tt + 1));  // seq 65: hA(+noise) visible

    // ---------- decoder; ys[t] doubles as the bf16 hidden chain ----------
#pragma unroll 1
    for (int t = 0; t < Tt; ++t) {
        zacc();
        if (t > 0) xp_phase(embF + (size_t)(t - 1) * Bb * Ee);
        hw_phase(t ? ys + (size_t)(t - 1) * Bb * Hh : hA, (unsigned)(Tt + 1 + t));  // seq 65+t
        epi(ys + (size_t)t * Bb * Hh);
        if (t < Tt - 1) signal((unsigned)(Tt + 2 + t));  // seq 66..128
    }
}

// ---------------- out = ys @ W_out + b_out; 64 rows/wave ----------------
__global__ __launch_bounds__(256) void k_out(const bf16* __restrict__ ys, const bf16* __restrict__ WT,
                                             const float* __restrict__ bias, float* __restrict__ out) {
    const int lane = threadIdx.x & 63, wv = threadIdx.x >> 6;
    const int m0w = blockIdx.x * 256 + wv * 64;
    const int c0 = blockIdx.y * 64;
    const int koff = (lane >> 4) * 8;
    f32x4 acc[4][4];
#pragma unroll
    for (int m = 0; m < 4; ++m)
#pragma unroll
        for (int s = 0; s < 4; ++s) acc[m][s] = f32x4{0.f, 0.f, 0.f, 0.f};

    const bf16* ap = ys + (size_t)(m0w + (lane & 15)) * Hh + koff;
#pragma unroll
    for (int kc = 0; kc < 16; ++kc) {
        bf16x8 a0 = *(const bf16x8*)(ap + kc * 32);
        bf16x8 a1 = *(const bf16x8*)(ap + 16 * Hh + kc * 32);
        bf16x8 a2 = *(const bf16x8*)(ap + 32 * Hh + kc * 32);
        bf16x8 a3 = *(const bf16x8*)(ap + 48 * Hh + kc * 32);
#pragma unroll
        for (int s = 0; s < 4; ++s) {
            bf16x8 b = *(const bf16x8*)(WT + (size_t)(c0 + s * 16 + (lane & 15)) * Hh + kc * 32 + koff);
            acc[0][s] = __builtin_amdgcn_mfma_f32_16x16x32_bf16(a0, b, acc[0][s], 0, 0, 0);
            acc[1][s] = __builtin_amdgcn_mfma_f32_16x16x32_bf16(a1, b, acc[1][s], 0, 0, 0);
            acc[2][s] = __builtin_amdgcn_mfma_f32_16x16x32_bf16(a2, b, acc[2][s], 0, 0, 0);
            acc[3][s] = __builtin_amdgcn_mfma_f32_16x16x32_bf16(a3, b, acc[3][s], 0, 0, 0);
        }
    }
#pragma unroll
    for (int m = 0; m < 4; ++m)
#pragma unroll
        for (int s = 0; s < 4; ++s) {
            int col = c0 + s * 16 + (lane & 15);
            float bv = bias[col];
#pragma unroll
            for (int r = 0; r < 4; ++r) {
                int row = m0w + m * 16 + (lane >> 4) * 4 + r;
                out[(size_t)row * Dd + col] = acc[m][s][r] + bv;
            }
        }
}

extern "C" void kernel_launch(void* const* d_in, const int* in_sizes, int n_in,
                              void* d_out, int out_size, void* d_ws, size_t ws_size,
                              hipStream_t stream) {
    const float* past = (const float*)d_in[0];
    const float* fut = (const float*)d_in[1];
    const float* noise = (const float*)d_in[2];
    const float* W_emb = (const float*)d_in[3];
    const float* b_emb = (const float*)d_in[4];
    const float* W_ih_enc = (const float*)d_in[5];
    const float* W_hh_enc = (const float*)d_in[6];
    const float* b_ih_enc = (const float*)d_in[7];
    const float* b_hh_enc = (const float*)d_in[8];
    const float* W_ih_dec = (const float*)d_in[9];
    const float* W_hh_dec = (const float*)d_in[10];
    const float* b_ih_dec = (const float*)d_in[11];
    const float* b_hh_dec = (const float*)d_in[12];
    const float* W_out = (const float*)d_in[13];
    const float* b_out = (const float*)d_in[14];
    float* out = (float*)d_out;

    char* w = (char*)d_ws;
    auto alloc = [&](size_t bytes) {
        char* p = w;
        w += (bytes + 255) & ~(size_t)255;
        return p;
    };
    bf16* embP = (bf16*)alloc((size_t)Tt * Bb * Ee * 2);
    bf16* embF = (bf16*)alloc((size_t)Tt * Bb * Ee * 2);
    bf16* ys = (bf16*)alloc((size_t)Tt * Bb * Hh * 2);
    bf16* hA = (bf16*)alloc((size_t)Bb * Hh * 2);
    bf16* hB = (bf16*)alloc((size_t)Bb * Hh * 2);
    bf16* WembT = (bf16*)alloc((size_t)Ee * Dd * 2);
    bf16* WihEncT = (bf16*)alloc((size_t)H3 * Ee * 2);
    bf16* WhhEncT = (bf16*)alloc((size_t)H3 * Hh * 2);
    bf16* WihDecT = (bf16*)alloc((size_t)H3 * Ee * 2);
    bf16* WhhDecT = (bf16*)alloc((size_t)H3 * Hh * 2);
    bf16* WoutT = (bf16*)alloc((size_t)Dd * Hh * 2);
    unsigned* flags = (unsigned*)alloc(16 * 2 * 32 * 16 * sizeof(unsigned));  // [im][rh][32], 64B stride

    // weight prep (all six transposes fused)
    k_prep<<<9600, 256, 0, stream>>>(W_emb, W_ih_enc, W_hh_enc, W_ih_dec, W_hh_dec, W_out,
                                     WembT, WihEncT, WhhEncT, WihDecT, WhhDecT, WoutT);

    // embeddings (past + future fused)
    k_embed<<<dim3(Tt * Bb / 128, Ee / 64, 2), 256, 0, stream>>>(past, fut, WembT, b_emb, embP, embF);

    // reset sequence flags
    hipMemsetAsync(flags, 0, 16 * 2 * 32 * 16 * sizeof(unsigned), stream);

    // cooperative persistent recurrent kernel: 256 blocks x 256 threads
    void* args[] = {(void*)&embP, (void*)&embF, (void*)&noise,
                    (void*)&WihEncT, (void*)&WhhEncT, (void*)&b_ih_enc, (void*)&b_hh_enc,
                    (void*)&WihDecT, (void*)&WhhDecT, (void*)&b_ih_dec, (void*)&b_hh_dec,
                    (void*)&hA, (void*)&hB, (void*)&ys, (void*)&flags};
    hipLaunchCooperativeKernel((const void*)k_gru_all, dim3(256), dim3(256), args, 0, stream);

    // output projection
    k_out<<<dim3(Tt * Bb / 256, Dd / 64), 256, 0, stream>>>(ys, WoutT, b_out, out);
}